// Round 5
// baseline (5656.632 us; speedup 1.0000x reference)
//
#include <hip/hip_runtime.h>
#include <hip/hip_fp16.h>

#define TT   2048
#define EMBD 256
#define HD   256      // H2
#define NG   1024     // 4*H2
#define NC   12
#define NEGV -10000.0f

typedef _Float16 half2v __attribute__((ext_vector_type(2)));
typedef _Float16 f16x8  __attribute__((ext_vector_type(8)));
typedef float    f32x4  __attribute__((ext_vector_type(4)));

// ---- static device scratch ----
__device__ float g_P[2 * TT * NG];   // input-GEMM preactivations, permuted: gate ga of unit u at 4u+ga (16 MB)
__device__ float g_HS[2 * TT * HD];  // hidden states both dirs (4 MB)
__device__ float g_FE[TT * NC];      // CRF emission feats (96 KB)
__device__ uint4 g_W7[2 * 8 * 6 * 64];  // kt7 A-frags rt2..7, [d][w][rt-2][lane] (96 KB, L2-resident)

__device__ __forceinline__ unsigned int f2h2(float a, float b) {
  half2v h; h.x = (_Float16)a; h.y = (_Float16)b;
  return __builtin_bit_cast(unsigned int, h);
}
__device__ __forceinline__ f16x8 asf16x8(uint4 v) { return __builtin_bit_cast(f16x8, v); }
__device__ __forceinline__ float fsigmoid(float x) { return 1.0f / (1.0f + __expf(-x)); }
__device__ __forceinline__ float ftanh(float x) {
  float a = fabsf(x);
  float e = __expf(-2.0f * a);
  float r = (1.0f - e) / (1.0f + e);
  return copysignf(r, x);
}

// Row permutation shared by k_input (writer) and k_rec (reader):
// original gate-row g = ga*256 + u  ->  permuted row r' = 4*u + ga
// (so P for unit u is one contiguous float4 = (i,f,g,o))

// ---------------- K1: embedding gather + input GEMM (+ both biases), f32 ----------------
__global__ __launch_bounds__(256) void k_input(
    const int* __restrict__ sent, const float* __restrict__ emb,
    const float* __restrict__ WihF, const float* __restrict__ bihF,
    const float* __restrict__ bhhF,
    const float* __restrict__ WihB, const float* __restrict__ bihB,
    const float* __restrict__ bhhB)
{
  const int d  = blockIdx.x & 1;
  const int t0 = (blockIdx.x >> 1) * 16;
  const float* Wih = d ? WihB : WihF;
  const float* bih = d ? bihB : bihF;
  const float* bhh = d ? bhhB : bhhF;
  __shared__ float xs[16][EMBD];
  for (int i = threadIdx.x; i < 16 * (EMBD / 4); i += 256) {
    const int tt = i >> 6, e4 = i & 63;
    reinterpret_cast<float4*>(xs[tt])[e4] =
        reinterpret_cast<const float4*>(emb + (size_t)sent[t0 + tt] * EMBD)[e4];
  }
  __syncthreads();
  for (int gg = 0; gg < 4; ++gg) {
    const int g = threadIdx.x + gg * 256;
    const float bias = bih[g] + bhh[g];
    float acc[16];
#pragma unroll
    for (int tt = 0; tt < 16; ++tt) acc[tt] = 0.0f;
    const float* wr = Wih + (size_t)g * EMBD;
    for (int e = 0; e < EMBD; e += 4) {
      const float4 w = *reinterpret_cast<const float4*>(wr + e);
#pragma unroll
      for (int tt = 0; tt < 16; ++tt) {
        acc[tt] += w.x * xs[tt][e] + w.y * xs[tt][e + 1]
                 + w.z * xs[tt][e + 2] + w.w * xs[tt][e + 3];
      }
    }
    const int u = g & 255, ga = g >> 8;
    const int rp = 4 * u + ga;            // permuted row
    float* Pg = g_P + ((size_t)d * TT + t0) * NG + rp;
#pragma unroll
    for (int tt = 0; tt < 16; ++tt) Pg[(size_t)tt * NG] = acc[tt] + bias;
  }
}

// ---------------- K2: BiLSTM recurrence — MFMA, dual-channel weight stream ----------------
// 512 threads (8 waves, 2/SIMD), 1 block/direction (round-2 structure, proven).
// Per wave: 8 rowtiles x 16 gate-rows (= 32 units), K=256 as 8 k-tiles.
// kt0..5 resident in regs (192). Stream per step, two parallel channels:
//   LDS  (~85 B/cyc/CU): kt6 rt0..7 + kt7 rt0..1  (80 KB/step)
//   L2   (~57 B/cyc/CU): kt7 rt2..7 from g_W7     (48 KB/step)
// Streams have NO dependence on h -> ring-3 lookahead-2 prefetch, compile-time indices.
__global__ __launch_bounds__(512, 2) void k_rec(
    const float* __restrict__ WhhF, const float* __restrict__ WhhB,
    const float* __restrict__ h0g, const float* __restrict__ c0g)
{
  __shared__ __align__(16) uint4 wlds[8][10][64];      // 80 KB: [w][slot][lane]; slot<8: kt6 rt, slot 8/9: kt7 rt0/1
  __shared__ __align__(16) unsigned short h2[2][256];  // 1 KB: f16 h, double buffered
  __shared__ __align__(16) float gates[256][4];        // 4 KB: (i,f,g,o) per unit

  const int d = blockIdx.x;
  const float* __restrict__ Whh = d ? WhhB : WhhF;
  const int tid  = threadIdx.x;
  const int w    = tid >> 6;
  const int lane = tid & 63;
  const int kg   = lane >> 4;        // k-group 0..3 (A/B: k = kt*32 + kg*8 + j)
  const int m    = lane & 15;        // A-row within 16-tile (m = lg*4 + ga)
  const int lg   = m >> 2, ga = m & 3;

  // ---- pack A fragments f32 -> f16: kt0..5 regs, kt6 + kt7(rt<2) LDS, kt7(rt>=2) global ----
  uint4 Ares[8][6];
#pragma unroll
  for (int rt = 0; rt < 8; ++rt) {
    const int orow = (ga << 8) + (w << 5) + (rt << 2) + lg;  // original Whh row
    const float* wr = Whh + (size_t)orow * HD;
#pragma unroll
    for (int kt = 0; kt < 8; ++kt) {
      const int k0 = (kt << 5) + (kg << 3);
      const float4 x0 = *reinterpret_cast<const float4*>(wr + k0);
      const float4 x1 = *reinterpret_cast<const float4*>(wr + k0 + 4);
      uint4 f;
      f.x = f2h2(x0.x, x0.y); f.y = f2h2(x0.z, x0.w);
      f.z = f2h2(x1.x, x1.y); f.w = f2h2(x1.z, x1.w);
      if (kt < 6)            Ares[rt][kt] = f;
      else if (kt == 6)      wlds[w][rt][lane] = f;
      else if (rt < 2)       wlds[w][8 + rt][lane] = f;
      else                   g_W7[(size_t)(((d << 3) + w) * 6 + (rt - 2)) * 64 + lane] = f;
    }
  }
  if (tid < 128)
    reinterpret_cast<unsigned int*>(h2[0])[tid] =
        f2h2(h0g[d * HD + 2 * tid], h0g[d * HD + 2 * tid + 1]);
  float c = (tid < 256) ? c0g[d * HD + tid] : 0.0f;   // lane tid<256 owns unit u=tid
  __syncthreads();   // also drains vmcnt -> g_W7 stores visible to own reads

  const float* Pbase = g_P + (size_t)d * TT * NG + 4 * tid;  // unit u=tid (tid<256)
  const uint4* wl = &wlds[w][0][lane];                       // LDS stream base
  const unsigned int w7base = (unsigned int)((((d << 3) + w) * 6) * 64 + lane);

  int t = d ? (TT - 1) : 0;
  const int tstep = d ? -1 : 1;
  float4 Pc = {0.f, 0.f, 0.f, 0.f};
  if (tid < 256) Pc = *reinterpret_cast<const float4*>(Pbase + (size_t)t * NG);
  int p = 0;

  for (int it = 0; it < TT; ++it, t += tstep) {
    // opaque offset: force the (step-invariant) L2 stream to re-issue every step
    unsigned int w7o = w7base;
    asm volatile("" : "+v"(w7o));

    // B fragments: h(t-1) f16x8 slices, broadcast within 16-lane groups
    f16x8 bf[8];
#pragma unroll
    for (int kt = 0; kt < 8; ++kt)
      bf[kt] = asf16x8(*reinterpret_cast<const uint4*>(&h2[p][(kt << 5) + (kg << 3)]));

    // stream rings: lookahead 2, ring 3 (all indices compile-time under full unroll)
    uint4 s6r[3], s7r[3];
    s6r[0] = wl[0 * 64];  s6r[1] = wl[1 * 64];
    s7r[0] = wl[8 * 64];  s7r[1] = wl[9 * 64];

#pragma unroll
    for (int rt = 0; rt < 8; ++rt) {
      if (rt + 2 < 8) {
        s6r[(rt + 2) % 3] = wl[(rt + 2) * 64];
        s7r[(rt + 2) % 3] = g_W7[w7o + rt * 64];   // frag for rowtile rt+2
      }
      f32x4 acc = {0.f, 0.f, 0.f, 0.f};
#pragma unroll
      for (int kt = 0; kt < 6; ++kt)
        acc = __builtin_amdgcn_mfma_f32_16x16x32_f16(asf16x8(Ares[rt][kt]), bf[kt], acc, 0, 0, 0);
      acc = __builtin_amdgcn_mfma_f32_16x16x32_f16(asf16x8(s6r[rt % 3]), bf[6], acc, 0, 0, 0);
      acc = __builtin_amdgcn_mfma_f32_16x16x32_f16(asf16x8(s7r[rt % 3]), bf[7], acc, 0, 0, 0);
      // D: row = kg*4 + reg -> unit w*32 + rt*4 + kg holds (i,f,g,o) in regs 0..3
      if (m == 0)
        *reinterpret_cast<float4*>(gates[(w << 5) + (rt << 2) + kg]) =
            __builtin_bit_cast(float4, acc);
    }
    // barrier 1: gates ready (LDS-only drain; global loads/stores stay in flight)
    asm volatile("s_waitcnt lgkmcnt(0)" ::: "memory");
    __builtin_amdgcn_s_barrier();
    __builtin_amdgcn_sched_barrier(0);

    if (tid < 256) {   // waves 0..3: cell update, one lane per unit
      const float4 gv = *reinterpret_cast<const float4*>(gates[tid]);
      const float gi = gv.x + Pc.x;
      const float gf = gv.y + Pc.y;
      const float gz = gv.z + Pc.z;
      const float go = gv.w + Pc.w;
      c = fsigmoid(gf) * c + fsigmoid(gi) * ftanh(gz);
      const float hh = fsigmoid(go) * ftanh(c);
      g_HS[((size_t)d * TT + t) * HD + tid] = hh;          // f32 for feats
      h2[p ^ 1][tid] = __builtin_bit_cast(unsigned short, (_Float16)hh);
      // reload P for next step: a full step of latency cover
      const int tn = (it + 1 < TT) ? (t + tstep) : t;
      Pc = *reinterpret_cast<const float4*>(Pbase + (size_t)tn * NG);
    }
    p ^= 1;
    // barrier 2: h2 ready for next step's B-frag reads (LDS-only drain)
    asm volatile("s_waitcnt lgkmcnt(0)" ::: "memory");
    __builtin_amdgcn_s_barrier();
    __builtin_amdgcn_sched_barrier(0);
  }
}

// ---------------- K3: feats = [hf;hb] @ Wlin^T + blin (pure f32) ----------------
__global__ __launch_bounds__(256) void k_feats(
    const float* __restrict__ Wlin, const float* __restrict__ blin)
{
  const int gid = blockIdx.x * 256 + threadIdx.x;
  if (gid >= TT * NC) return;
  const int t = gid / NC, cc = gid - t * NC;
  const float* hf = g_HS + (size_t)t * HD;
  const float* hb = g_HS + ((size_t)TT + t) * HD;
  const float* wr = Wlin + cc * 512;
  float acc = blin[cc];
  for (int j = 0; j < HD; j += 4) {
    const float4 w = *reinterpret_cast<const float4*>(wr + j);
    acc += w.x * hf[j] + w.y * hf[j + 1] + w.z * hf[j + 2] + w.w * hf[j + 3];
  }
  for (int j = 0; j < HD; j += 4) {
    const float4 w = *reinterpret_cast<const float4*>(wr + 256 + j);
    acc += w.x * hb[j] + w.y * hb[j + 1] + w.z * hb[j + 2] + w.w * hb[j + 3];
  }
  g_FE[gid] = acc;
}

// ---------------- K4: Viterbi + backtrace (single wave); f32 in/out ----------------
// Lane-parallel forward: lane j keeps fv[j]; same add/compare order as before
// (ascending i, strict >) -> bit-identical bp/score, fewer cross-lane ops.
__global__ __launch_bounds__(64) void k_vit(
    const float* __restrict__ trans, float* __restrict__ out)
{
  const int lane = threadIdx.x;
  const bool act = lane < NC;
  __shared__ unsigned char bp[TT][NC];
  float Trow[NC];
#pragma unroll
  for (int i = 0; i < NC; ++i) Trow[i] = act ? trans[lane * NC + i] : NEGV;
  float fv = (lane == 10) ? 0.0f : NEGV;   // START=10

  float f0 = act ? g_FE[lane] : 0.0f;                 // 2-deep FE prefetch
  float f1 = act ? g_FE[NC + lane] : 0.0f;
  for (int t = 0; t < TT; ++t) {
    const float feat = f0;
    f0 = f1;
    f1 = (act && t + 2 < TT) ? g_FE[(t + 2) * NC + lane] : 0.0f;
    float best = __shfl(fv, 0) + Trow[0]; int bi = 0;
#pragma unroll
    for (int i = 1; i < NC; ++i) {
      const float s = __shfl(fv, i) + Trow[i];
      if (s > best) { best = s; bi = i; }   // strict > == jnp first-max tiebreak
    }
    if (act) bp[t][lane] = (unsigned char)bi;
    fv = best + feat;
  }
  // terminal = fv + transitions[STOP=11] (row 11)
  const float term = act ? (fv + trans[11 * NC + lane]) : -3.0e38f;
  float tv[NC];
#pragma unroll
  for (int i = 0; i < NC; ++i) tv[i] = __shfl(term, i);
  if (lane == 0) {
    float bs = tv[0]; int bt = 0;
#pragma unroll
    for (int i = 1; i < NC; ++i) if (tv[i] > bs) { bs = tv[i]; bt = i; }
    out[0] = bs;                             // f32 path_score
    int tag = bt;
    for (int t = TT - 1; t >= 0; --t) {
      out[1 + t] = (float)tag;               // path tags as f32
      tag = bp[t][tag];
    }
  }
}

extern "C" void kernel_launch(void* const* d_in, const int* in_sizes, int n_in,
                              void* d_out, int out_size, void* d_ws, size_t ws_size,
                              hipStream_t stream) {
  const int*   sent = (const int*)d_in[0];
  const float* emb  = (const float*)d_in[1];
  const float* WihF = (const float*)d_in[2];
  const float* WhhF = (const float*)d_in[3];
  const float* bihF = (const float*)d_in[4];
  const float* bhhF = (const float*)d_in[5];
  const float* WihB = (const float*)d_in[6];
  const float* WhhB = (const float*)d_in[7];
  const float* bihB = (const float*)d_in[8];
  const float* bhhB = (const float*)d_in[9];
  const float* Wlin = (const float*)d_in[10];
  const float* blin = (const float*)d_in[11];
  const float* h0g  = (const float*)d_in[12];
  const float* c0g  = (const float*)d_in[13];
  const float* trans= (const float*)d_in[14];
  (void)d_ws; (void)ws_size; (void)in_sizes; (void)n_in; (void)out_size;

  k_input<<<dim3(2 * (TT / 16)), dim3(256), 0, stream>>>(
      sent, emb, WihF, bihF, bhhF, WihB, bihB, bhhB);

  k_rec<<<dim3(2), dim3(512), 0, stream>>>(WhhF, WhhB, h0g, c0g);

  k_feats<<<dim3((TT * NC + 255) / 256), dim3(256), 0, stream>>>(Wlin, blin);

  k_vit<<<dim3(1), dim3(64), 0, stream>>>(trans, (float*)d_out);
}

// Round 6
// 5636.214 us; speedup vs baseline: 1.0036x; 1.0036x over previous
//
#include <hip/hip_runtime.h>
#include <hip/hip_fp16.h>

#define TT   2048
#define EMBD 256
#define HD   256      // H2
#define NG   1024     // 4*H2
#define NC   12
#define NEGV -10000.0f

typedef _Float16 half2v __attribute__((ext_vector_type(2)));
typedef _Float16 f16x8  __attribute__((ext_vector_type(8)));
typedef float    f32x4  __attribute__((ext_vector_type(4)));

// ---- static device scratch ----
__device__ float g_P[2 * TT * NG];   // input-GEMM preactivations, permuted: gate ga of unit u at 4u+ga (16 MB)
__device__ float g_HS[2 * TT * HD];  // hidden states both dirs (4 MB)
__device__ float g_FE[TT * NC];      // CRF emission feats (96 KB)

__device__ __forceinline__ unsigned int f2h2(float a, float b) {
  half2v h; h.x = (_Float16)a; h.y = (_Float16)b;
  return __builtin_bit_cast(unsigned int, h);
}
__device__ __forceinline__ f16x8 asf16x8(uint4 v) { return __builtin_bit_cast(f16x8, v); }
__device__ __forceinline__ float fsigmoid(float x) { return 1.0f / (1.0f + __expf(-x)); }
__device__ __forceinline__ float ftanh(float x) {
  float a = fabsf(x);
  float e = __expf(-2.0f * a);
  float r = (1.0f - e) / (1.0f + e);
  return copysignf(r, x);
}

// Row permutation shared by k_input (writer) and k_rec (reader):
// original gate-row g = ga*256 + u  ->  permuted row r' = 4*u + ga
// (so P for unit u is one contiguous float4 = (i,f,g,o))

// ---------------- K1: embedding gather + input GEMM (+ both biases), f32 ----------------
__global__ __launch_bounds__(256) void k_input(
    const int* __restrict__ sent, const float* __restrict__ emb,
    const float* __restrict__ WihF, const float* __restrict__ bihF,
    const float* __restrict__ bhhF,
    const float* __restrict__ WihB, const float* __restrict__ bihB,
    const float* __restrict__ bhhB)
{
  const int d  = blockIdx.x & 1;
  const int t0 = (blockIdx.x >> 1) * 16;
  const float* Wih = d ? WihB : WihF;
  const float* bih = d ? bihB : bihF;
  const float* bhh = d ? bhhB : bhhF;
  __shared__ float xs[16][EMBD];
  for (int i = threadIdx.x; i < 16 * (EMBD / 4); i += 256) {
    const int tt = i >> 6, e4 = i & 63;
    reinterpret_cast<float4*>(xs[tt])[e4] =
        reinterpret_cast<const float4*>(emb + (size_t)sent[t0 + tt] * EMBD)[e4];
  }
  __syncthreads();
  for (int gg = 0; gg < 4; ++gg) {
    const int g = threadIdx.x + gg * 256;
    const float bias = bih[g] + bhh[g];
    float acc[16];
#pragma unroll
    for (int tt = 0; tt < 16; ++tt) acc[tt] = 0.0f;
    const float* wr = Wih + (size_t)g * EMBD;
    for (int e = 0; e < EMBD; e += 4) {
      const float4 w = *reinterpret_cast<const float4*>(wr + e);
#pragma unroll
      for (int tt = 0; tt < 16; ++tt) {
        acc[tt] += w.x * xs[tt][e] + w.y * xs[tt][e + 1]
                 + w.z * xs[tt][e + 2] + w.w * xs[tt][e + 3];
      }
    }
    const int u = g & 255, ga = g >> 8;
    const int rp = 4 * u + ga;            // permuted row
    float* Pg = g_P + ((size_t)d * TT + t0) * NG + rp;
#pragma unroll
    for (int tt = 0; tt < 16; ++tt) Pg[(size_t)tt * NG] = acc[tt] + bias;
  }
}

// ---------------- K2: BiLSTM recurrence — MFMA + LDS stream + IN-LANE cell update ----------------
// 512 threads (8 waves, 2/SIMD), 1 block/direction (r2 structure).
// Per wave: 8 rowtiles x 16 gate-rows (= 32 units), K=256 as 8 k-tiles.
// kt0..5 resident in regs (192), kt6..7 streamed from LDS (128 KB/step).
// Key change vs r2: D-fragment is replicated across the 16 broadcast columns, so
// lane (kg, m) already holds (i,f,g,o) of unit w*32+rt*4+kg for every rt.
// Lane m<8 captures rt==m via compile-time-unrolled selects and does the cell
// update IN-LANE: no gates LDS round-trip, ONE barrier per step instead of two.
__global__ __launch_bounds__(512, 2) void k_rec(
    const float* __restrict__ WhhF, const float* __restrict__ WhhB,
    const float* __restrict__ h0g, const float* __restrict__ c0g)
{
  __shared__ __align__(16) uint4 wlds[8][2][8][64];    // 128 KB: streamed A-frags [w][kt-6][rt][lane]
  __shared__ __align__(16) unsigned short h2[2][256];  // 1 KB: f16 h, double buffered

  const int d = blockIdx.x;
  const float* __restrict__ Whh = d ? WhhB : WhhF;
  const int tid  = threadIdx.x;
  const int w    = tid >> 6;
  const int lane = tid & 63;
  const int kg   = lane >> 4;        // k-group 0..3 (A/B: k = kt*32 + kg*8 + j)
  const int m    = lane & 15;        // A-row within 16-tile (m = lg*4 + ga)
  const int lg   = m >> 2, ga = m & 3;

  // ---- pack A fragments f32 -> f16: kt0..5 regs, kt6..7 LDS ----
  uint4 Ares[8][6];
#pragma unroll
  for (int rt = 0; rt < 8; ++rt) {
    const int orow = (ga << 8) + (w << 5) + (rt << 2) + lg;  // original Whh row
    const float* wr = Whh + (size_t)orow * HD;
#pragma unroll
    for (int kt = 0; kt < 8; ++kt) {
      const int k0 = (kt << 5) + (kg << 3);
      const float4 x0 = *reinterpret_cast<const float4*>(wr + k0);
      const float4 x1 = *reinterpret_cast<const float4*>(wr + k0 + 4);
      uint4 f;
      f.x = f2h2(x0.x, x0.y); f.y = f2h2(x0.z, x0.w);
      f.z = f2h2(x1.x, x1.y); f.w = f2h2(x1.z, x1.w);
      if (kt < 6) Ares[rt][kt] = f;
      else        wlds[w][kt - 6][rt][lane] = f;
    }
  }
  if (tid < 128)
    reinterpret_cast<unsigned int*>(h2[0])[tid] =
        f2h2(h0g[d * HD + 2 * tid], h0g[d * HD + 2 * tid + 1]);

  // this lane's owned unit (valid when m < 8): u = w*32 + m*4 + kg
  const int u = (w << 5) + ((m & 7) << 2) + kg;
  float c = 0.0f;
  if (m < 8) c = c0g[d * HD + u];
  __syncthreads();

  const float* Pu  = g_P  + (size_t)d * TT * NG + 4 * u;   // (i,f,g,o) of unit u at time t
  float*       HSu = g_HS + (size_t)d * TT * HD + u;

  int t = d ? (TT - 1) : 0;
  const int tstep = d ? -1 : 1;
  float4 Pc = {0.f, 0.f, 0.f, 0.f};
  if (m < 8) Pc = *reinterpret_cast<const float4*>(Pu + (size_t)t * NG);
  int p = 0;

  for (int it = 0; it < TT; ++it, t += tstep) {
    // B fragments: h(t-1) f16x8 slices, broadcast within 16-lane groups
    f16x8 bf[8];
#pragma unroll
    for (int kt = 0; kt < 8; ++kt)
      bf[kt] = asf16x8(*reinterpret_cast<const uint4*>(&h2[p][(kt << 5) + (kg << 3)]));

    f32x4 my = {0.f, 0.f, 0.f, 0.f};   // this lane's owned-unit gates (rt == m)
#pragma unroll
    for (int rt = 0; rt < 8; ++rt) {
      const uint4 s6 = wlds[w][0][rt][lane];   // streamed kt6
      const uint4 s7 = wlds[w][1][rt][lane];   // streamed kt7
      f32x4 acc = {0.f, 0.f, 0.f, 0.f};
#pragma unroll
      for (int kt = 0; kt < 6; ++kt)
        acc = __builtin_amdgcn_mfma_f32_16x16x32_f16(asf16x8(Ares[rt][kt]), bf[kt], acc, 0, 0, 0);
      acc = __builtin_amdgcn_mfma_f32_16x16x32_f16(asf16x8(s6), bf[6], acc, 0, 0, 0);
      acc = __builtin_amdgcn_mfma_f32_16x16x32_f16(asf16x8(s7), bf[7], acc, 0, 0, 0);
      // capture own rowtile (rt compile-time, m runtime -> 4 cndmasks, registers static)
      const bool sel = (rt == m);
      my.x = sel ? acc.x : my.x;
      my.y = sel ? acc.y : my.y;
      my.z = sel ? acc.z : my.z;
      my.w = sel ? acc.w : my.w;
    }

    // ---- in-lane cell update: lane (kg, m<8) owns unit u ----
    if (m < 8) {
      const float gi = my.x + Pc.x;
      const float gf = my.y + Pc.y;
      const float gz = my.z + Pc.z;
      const float go = my.w + Pc.w;
      c = fsigmoid(gf) * c + fsigmoid(gi) * ftanh(gz);
      const float hh = fsigmoid(go) * ftanh(c);
      HSu[(size_t)t * HD] = hh;                              // f32 for feats (async, never waited)
      h2[p ^ 1][u] = __builtin_bit_cast(unsigned short, (_Float16)hh);
      // reload P for next step: a full step of latency cover
      const int tn = (it + 1 < TT) ? (t + tstep) : t;
      Pc = *reinterpret_cast<const float4*>(Pu + (size_t)tn * NG);
    }
    p ^= 1;
    // single barrier per step: h2[p^1] writes visible before next step's bf reads
    asm volatile("s_waitcnt lgkmcnt(0)" ::: "memory");
    __builtin_amdgcn_s_barrier();
    __builtin_amdgcn_sched_barrier(0);
  }
}

// ---------------- K3: feats = [hf;hb] @ Wlin^T + blin (pure f32) ----------------
__global__ __launch_bounds__(256) void k_feats(
    const float* __restrict__ Wlin, const float* __restrict__ blin)
{
  const int gid = blockIdx.x * 256 + threadIdx.x;
  if (gid >= TT * NC) return;
  const int t = gid / NC, cc = gid - t * NC;
  const float* hf = g_HS + (size_t)t * HD;
  const float* hb = g_HS + ((size_t)TT + t) * HD;
  const float* wr = Wlin + cc * 512;
  float acc = blin[cc];
  for (int j = 0; j < HD; j += 4) {
    const float4 w = *reinterpret_cast<const float4*>(wr + j);
    acc += w.x * hf[j] + w.y * hf[j + 1] + w.z * hf[j + 2] + w.w * hf[j + 3];
  }
  for (int j = 0; j < HD; j += 4) {
    const float4 w = *reinterpret_cast<const float4*>(wr + 256 + j);
    acc += w.x * hb[j] + w.y * hb[j + 1] + w.z * hb[j + 2] + w.w * hb[j + 3];
  }
  g_FE[gid] = acc;
}

// ---------------- K4: Viterbi + backtrace (single wave); f32 in/out ----------------
// Lane-parallel forward: lane j keeps fv[j]; same add/compare order as reference
// (ascending i, strict >) -> identical bp/score.
__global__ __launch_bounds__(64) void k_vit(
    const float* __restrict__ trans, float* __restrict__ out)
{
  const int lane = threadIdx.x;
  const bool act = lane < NC;
  __shared__ unsigned char bp[TT][NC];
  float Trow[NC];
#pragma unroll
  for (int i = 0; i < NC; ++i) Trow[i] = act ? trans[lane * NC + i] : NEGV;
  float fv = (lane == 10) ? 0.0f : NEGV;   // START=10

  float f0 = act ? g_FE[lane] : 0.0f;                 // 2-deep FE prefetch
  float f1 = act ? g_FE[NC + lane] : 0.0f;
  for (int t = 0; t < TT; ++t) {
    const float feat = f0;
    f0 = f1;
    f1 = (act && t + 2 < TT) ? g_FE[(t + 2) * NC + lane] : 0.0f;
    float best = __shfl(fv, 0) + Trow[0]; int bi = 0;
#pragma unroll
    for (int i = 1; i < NC; ++i) {
      const float s = __shfl(fv, i) + Trow[i];
      if (s > best) { best = s; bi = i; }   // strict > == jnp first-max tiebreak
    }
    if (act) bp[t][lane] = (unsigned char)bi;
    fv = best + feat;
  }
  // terminal = fv + transitions[STOP=11] (row 11)
  const float term = act ? (fv + trans[11 * NC + lane]) : -3.0e38f;
  float tv[NC];
#pragma unroll
  for (int i = 0; i < NC; ++i) tv[i] = __shfl(term, i);
  if (lane == 0) {
    float bs = tv[0]; int bt = 0;
#pragma unroll
    for (int i = 1; i < NC; ++i) if (tv[i] > bs) { bs = tv[i]; bt = i; }
    out[0] = bs;                             // f32 path_score
    int tag = bt;
    for (int t = TT - 1; t >= 0; --t) {
      out[1 + t] = (float)tag;               // path tags as f32
      tag = bp[t][tag];
    }
  }
}

extern "C" void kernel_launch(void* const* d_in, const int* in_sizes, int n_in,
                              void* d_out, int out_size, void* d_ws, size_t ws_size,
                              hipStream_t stream) {
  const int*   sent = (const int*)d_in[0];
  const float* emb  = (const float*)d_in[1];
  const float* WihF = (const float*)d_in[2];
  const float* WhhF = (const float*)d_in[3];
  const float* bihF = (const float*)d_in[4];
  const float* bhhF = (const float*)d_in[5];
  const float* WihB = (const float*)d_in[6];
  const float* WhhB = (const float*)d_in[7];
  const float* bihB = (const float*)d_in[8];
  const float* bhhB = (const float*)d_in[9];
  const float* Wlin = (const float*)d_in[10];
  const float* blin = (const float*)d_in[11];
  const float* h0g  = (const float*)d_in[12];
  const float* c0g  = (const float*)d_in[13];
  const float* trans= (const float*)d_in[14];
  (void)d_ws; (void)ws_size; (void)in_sizes; (void)n_in; (void)out_size;

  k_input<<<dim3(2 * (TT / 16)), dim3(256), 0, stream>>>(
      sent, emb, WihF, bihF, bhhF, WihB, bihB, bhhB);

  k_rec<<<dim3(2), dim3(512), 0, stream>>>(WhhF, WhhB, h0g, c0g);

  k_feats<<<dim3((TT * NC + 255) / 256), dim3(256), 0, stream>>>(Wlin, blin);

  k_vit<<<dim3(1), dim3(64), 0, stream>>>(trans, (float*)d_out);
}